// Round 1
// baseline (7701.831 us; speedup 1.0000x reference)
//
#include <hip/hip_runtime.h>
#include <stdint.h>

#define ORIG   32000
#define NEWN   31199
#define DIM    1024
#define BB     4096
#define KNEG   10
#define MW_PAD 4096    // max unique new-W ids = |in_ids| = 4096
#define MV_PAD 32768   // max unique new-V ids = 31199, padded to chunk multiple

typedef __attribute__((ext_vector_type(8))) short bf16x8;
typedef __attribute__((ext_vector_type(4))) float f32x4;

__device__ __forceinline__ unsigned short f2bf(float f) {
  union { float f; unsigned u; } c; c.f = f;
  unsigned r = c.u + 0x7FFFu + ((c.u >> 16) & 1u);   // RNE
  return (unsigned short)(r >> 16);
}

// async global->LDS, 16B per lane; LDS dest = wave-uniform base + lane*16
__device__ __forceinline__ void async16(const void* g, void* l) {
  __builtin_amdgcn_global_load_lds(
      reinterpret_cast<__attribute__((address_space(1))) void*>(reinterpret_cast<uintptr_t>(g)),
      reinterpret_cast<__attribute__((address_space(3))) void*>(reinterpret_cast<uintptr_t>(l)),
      16, 0, 0);
}

// ---------- id marking / compaction ----------
__global__ __launch_bounds__(256) void mark_ids(const int* __restrict__ in_ids,
                                                const int* __restrict__ pos_ids,
                                                const int* __restrict__ neg_ids,
                                                int* __restrict__ flagW,
                                                int* __restrict__ flagV) {
  int i = blockIdx.x * 256 + threadIdx.x;           // 192 blocks * 256 = 49152 exact
  if (i < BB) { int v = in_ids[i];        if (v >= ORIG) flagW[v - ORIG] = 1; }
  else if (i < 2 * BB) { int v = pos_ids[i - BB];  if (v >= ORIG) flagV[v - ORIG] = 1; }
  else { int v = neg_ids[i - 2 * BB];     if (v >= ORIG) flagV[v - ORIG] = 1; }
}

__global__ __launch_bounds__(256) void compact(const int* __restrict__ flag,
                                               int* __restrict__ list,
                                               int* __restrict__ inv,
                                               int* __restrict__ cnt) {
  int j = blockIdx.x * 256 + threadIdx.x;
  if (j < NEWN && flag[j]) { int k = atomicAdd(cnt, 1); list[k] = j; inv[j] = k; }
}

// ---------- fp32 [R,C] -> bf16 [C,R] transpose-convert ----------
__global__ __launch_bounds__(256) void tcvt(const float* __restrict__ in,
                                            unsigned short* __restrict__ out,
                                            int R, int Cc) {
  __shared__ float tile[64][65];
  int c0 = blockIdx.x << 6, r0 = blockIdx.y << 6;
  int lc = threadIdx.x & 63, lw = threadIdx.x >> 6;
  for (int i = lw; i < 64; i += 4)
    tile[i][lc] = in[(size_t)(r0 + i) * Cc + c0 + lc];
  __syncthreads();
  for (int i = lw; i < 64; i += 4)
    out[(size_t)(c0 + i) * R + r0 + lc] = f2bf(tile[lc][i]);
}

// ---------- gather A1 rows (by compacted list) -> bf16 ----------
__global__ __launch_bounds__(256) void gather_rows(const float* __restrict__ src,
                                                   const int* __restrict__ list,
                                                   const int* __restrict__ cnt,
                                                   unsigned short* __restrict__ dst) {
  int row = blockIdx.x;
  if (row >= *cnt) return;
  int t = threadIdx.x;
  const float4* s = (const float4*)(src + (size_t)list[row] * DIM);
  float4 v = s[t];
  ushort4 o; o.x = f2bf(v.x); o.y = f2bf(v.y); o.z = f2bf(v.z); o.w = f2bf(v.w);
  ((ushort4*)(dst + (size_t)row * DIM))[t] = o;
}

// ---------- bf16 MFMA GEMM: C[M,N](fp32) = A[M,K] * BT[N,K]^T ----------
// 128x128 tile, BK=32, 4 waves each 64x64. ATOMIC=1: atomicAdd epilogue (split-K).
template<int ATOMIC>
__global__ __launch_bounds__(256) void gemm_bt(const unsigned short* __restrict__ A, int ldA,
                                               const unsigned short* __restrict__ BT, int ldBT,
                                               float* __restrict__ C, int ldC,
                                               const int* __restrict__ cnt, int base, int kseg) {
  int valid = *cnt - base;
  if ((int)blockIdx.y * 128 >= valid) return;       // empty tail tiles exit
  __shared__ __align__(16) unsigned short ldsA[128 * 32];
  __shared__ __align__(16) unsigned short ldsB[128 * 32];
  int t = threadIdx.x;
  int lane = t & 63, wave = t >> 6;
  int lr = lane & 15, lq = lane >> 4;
  int wm = (wave & 1) << 6, wn = (wave >> 1) << 6;
  int m0 = blockIdx.y * 128, n0 = blockIdx.x * 128;
  int k0start = blockIdx.z * kseg;
  int srow = t >> 2, sseg = (t & 3) << 3;           // 4 lanes x 16B cover one 64B row of BK=32
  const unsigned short* gA0 = A + (size_t)(m0 + srow) * ldA + sseg + k0start;
  const unsigned short* gA1 = A + (size_t)(m0 + 64 + srow) * ldA + sseg + k0start;
  const unsigned short* gB0 = BT + (size_t)(n0 + srow) * ldBT + sseg + k0start;
  const unsigned short* gB1 = BT + (size_t)(n0 + 64 + srow) * ldBT + sseg + k0start;
  unsigned short* lA0 = ldsA + t * 8;
  unsigned short* lA1 = ldsA + 2048 + t * 8;
  unsigned short* lB0 = ldsB + t * 8;
  unsigned short* lB1 = ldsB + 2048 + t * 8;
  f32x4 acc[4][4] = {};
  for (int k0 = 0; k0 < kseg; k0 += 32) {
    async16(gA0 + k0, lA0);
    async16(gA1 + k0, lA1);
    async16(gB0 + k0, lB0);
    async16(gB1 + k0, lB1);
    __syncthreads();                                 // drains vmcnt (global_load_lds)
    bf16x8 af[4], bff[4];
#pragma unroll
    for (int i = 0; i < 4; i++) {
      af[i]  = *reinterpret_cast<const bf16x8*>(ldsA + ((wm + i * 16 + lr) << 5) + (lq << 3));
      bff[i] = *reinterpret_cast<const bf16x8*>(ldsB + ((wn + i * 16 + lr) << 5) + (lq << 3));
    }
#pragma unroll
    for (int i = 0; i < 4; i++)
#pragma unroll
      for (int j = 0; j < 4; j++)
        acc[i][j] = __builtin_amdgcn_mfma_f32_16x16x32_bf16(af[i], bff[j], acc[i][j], 0, 0, 0);
    __syncthreads();
  }
  // C/D layout: col = lane&15, row = (lane>>4)*4 + reg
#pragma unroll
  for (int i = 0; i < 4; i++) {
#pragma unroll
    for (int r = 0; r < 4; r++) {
      int row = m0 + wm + i * 16 + lq * 4 + r;
      float* crow = C + (size_t)row * ldC + n0 + wn + lr;
#pragma unroll
      for (int j = 0; j < 4; j++) {
        float v = acc[i][j][r];
        if (ATOMIC) atomicAdd(&crow[j * 16], v);
        else        crow[j * 16] = v;
      }
    }
  }
}

// ---------- row softmax: fp32 logits -> bf16 unnormalized exp + fp32 denom ----------
__global__ __launch_bounds__(256) void softmax_rows(const float* __restrict__ L,
                                                    unsigned short* __restrict__ P,
                                                    float* __restrict__ sums,
                                                    const int* __restrict__ cnt, int base) {
  int row = blockIdx.x;
  if (row >= *cnt - base) return;
  int t = threadIdx.x;
  const float4* x4 = (const float4*)(L + (size_t)row * ORIG);
  float m = -3.4e38f;
  for (int i = t; i < ORIG / 4; i += 256) {
    float4 v = x4[i];
    m = fmaxf(m, fmaxf(fmaxf(v.x, v.y), fmaxf(v.z, v.w)));
  }
  __shared__ float red[4];
  for (int off = 32; off; off >>= 1) m = fmaxf(m, __shfl_down(m, off, 64));
  if ((t & 63) == 0) red[t >> 6] = m;
  __syncthreads();
  m = fmaxf(fmaxf(red[0], red[1]), fmaxf(red[2], red[3]));
  __syncthreads();
  float s = 0.f;
  ushort4* p4 = (ushort4*)(P + (size_t)row * ORIG);
  for (int i = t; i < ORIG / 4; i += 256) {
    float4 v = x4[i];
    float e0 = __expf(v.x - m), e1 = __expf(v.y - m), e2 = __expf(v.z - m), e3 = __expf(v.w - m);
    s += (e0 + e1) + (e2 + e3);
    ushort4 o; o.x = f2bf(e0); o.y = f2bf(e1); o.z = f2bf(e2); o.w = f2bf(e3);
    p4[i] = o;
  }
  for (int off = 32; off; off >>= 1) s += __shfl_down(s, off, 64);
  if ((t & 63) == 0) red[t >> 6] = s;
  __syncthreads();
  if (t == 0) sums[row] = (red[0] + red[1]) + (red[2] + red[3]);
}

// ---------- divide E rows by softmax denominator ----------
__global__ __launch_bounds__(256) void scale_rows(float* __restrict__ E,
                                                  const float* __restrict__ sums,
                                                  const int* __restrict__ cnt) {
  int row = blockIdx.x;
  if (row >= *cnt) return;
  float rs = 1.0f / sums[row];
  float4* e4 = (float4*)(E + (size_t)row * DIM);
  float4 v = e4[threadIdx.x];
  v.x *= rs; v.y *= rs; v.z *= rs; v.w *= rs;
  e4[threadIdx.x] = v;
}

// ---------- final scoring: one block per b ----------
__global__ __launch_bounds__(256) void score_loss(const float* __restrict__ Wo,
                                                  const float* __restrict__ Vo,
                                                  const float* __restrict__ EW,
                                                  const float* __restrict__ EV,
                                                  const int* __restrict__ invW,
                                                  const int* __restrict__ invV,
                                                  const int* __restrict__ in_ids,
                                                  const int* __restrict__ pos_ids,
                                                  const int* __restrict__ neg_ids,
                                                  float* __restrict__ acc) {
  int b = blockIdx.x, t = threadIdx.x;
  int i = in_ids[b];
  const float4* ein = (const float4*)((i < ORIG) ? Wo + (size_t)i * DIM
                                                 : EW + (size_t)invW[i - ORIG] * DIM);
  float4 x = ein[t];
  int p = pos_ids[b];
  const float4* ep = (const float4*)((p < ORIG) ? Vo + (size_t)p * DIM
                                                : EV + (size_t)invV[p - ORIG] * DIM);
  float4 y = ep[t];
  float spos = x.x * y.x + x.y * y.y + x.z * y.z + x.w * y.w;
  float sneg = 0.f;
  for (int k = 0; k < KNEG; k++) {
    int nid = neg_ids[b * KNEG + k];
    const float4* en = (const float4*)((nid < ORIG) ? Vo + (size_t)nid * DIM
                                                    : EV + (size_t)invV[nid - ORIG] * DIM);
    float4 z = en[t];
    sneg += x.x * z.x + x.y * z.y + x.z * z.z + x.w * z.w;
  }
  __shared__ float redA[4], redB[4];
  for (int off = 32; off; off >>= 1) {
    spos += __shfl_down(spos, off, 64);
    sneg += __shfl_down(sneg, off, 64);
  }
  int lane = t & 63, wv = t >> 6;
  if (lane == 0) { redA[wv] = spos; redB[wv] = sneg; }
  __syncthreads();
  if (t == 0) {
    spos = (redA[0] + redA[1]) + (redA[2] + redA[3]);
    sneg = (redB[0] + redB[1]) + (redB[2] + redB[3]);
    // -log_sigmoid(x) = softplus(-x);  softplus(x) = max(x,0) + log1p(exp(-|x|))
    float pl = fmaxf(-spos, 0.f) + log1pf(__expf(-fabsf(spos)));
    float nl = fmaxf(sneg, 0.f) + log1pf(__expf(-fabsf(sneg)));
    atomicAdd(acc, pl + nl);
  }
}

__global__ void finalize(const float* __restrict__ acc, float* __restrict__ out) {
  if (threadIdx.x == 0) out[0] = acc[0] * (1.0f / (float)BB);
}

extern "C" void kernel_launch(void* const* d_in, const int* in_sizes, int n_in,
                              void* d_out, int out_size, void* d_ws, size_t ws_size,
                              hipStream_t stream) {
  (void)in_sizes; (void)n_in; (void)out_size;
  const float* Wo  = (const float*)d_in[0];
  const float* Vo  = (const float*)d_in[1];
  const float* AW1 = (const float*)d_in[2];
  const float* AW2 = (const float*)d_in[3];
  const float* AV1 = (const float*)d_in[4];
  const float* AV2 = (const float*)d_in[5];
  const int* in_ids  = (const int*)d_in[6];
  const int* pos_ids = (const int*)d_in[7];
  const int* neg_ids = (const int*)d_in[8];
  float* out = (float*)d_out;

  char* basep = (char*)d_ws;
  size_t off = 0;
  auto alloc = [&](size_t bytes) -> char* {
    char* r = basep + off;
    off = (off + bytes + 255) & ~(size_t)255;
    return r;
  };
  int* hdr     = (int*)alloc(256);                    // [0]=cntW [1]=cntV [2]=loss acc (f32)
  int* flagW   = (int*)alloc((size_t)NEWN * 4);
  int* flagV   = (int*)alloc((size_t)NEWN * 4);
  size_t zero_bytes = off;                            // zeroed every launch
  int* listW   = (int*)alloc((size_t)MW_PAD * 4);
  int* listV   = (int*)alloc((size_t)(NEWN + 64) * 4);
  int* invW    = (int*)alloc((size_t)NEWN * 4);
  int* invV    = (int*)alloc((size_t)NEWN * 4);
  float* sumsW = (float*)alloc((size_t)MW_PAD * 4);
  float* sumsV = (float*)alloc((size_t)MV_PAD * 4);
  unsigned short* A1Wg = (unsigned short*)alloc((size_t)MW_PAD * DIM * 2);
  unsigned short* A1Vg = (unsigned short*)alloc((size_t)MV_PAD * DIM * 2);
  float* EW    = (float*)alloc((size_t)MW_PAD * DIM * 4);
  float* EV    = (float*)alloc((size_t)MV_PAD * DIM * 4);
  unsigned short* AW2T = (unsigned short*)alloc((size_t)ORIG * DIM * 2);  // [32000,1024]
  unsigned short* AV2T = (unsigned short*)alloc((size_t)ORIG * DIM * 2);
  unsigned short* WoT  = (unsigned short*)alloc((size_t)DIM * ORIG * 2);  // [1024,32000]
  unsigned short* VoT  = (unsigned short*)alloc((size_t)DIM * ORIG * 2);
  size_t fixed_end = off;

  // pick the largest logits/probs chunk (rows) that fits the workspace
  const int cands[5] = {4096, 2048, 1024, 512, 256};
  int Mc = 128;
  for (int ci = 0; ci < 5; ++ci) {
    size_t need = fixed_end + (size_t)cands[ci] * ORIG * 6 + 1024;
    if (need <= ws_size) { Mc = cands[ci]; break; }
  }
  float* logits = (float*)alloc((size_t)Mc * ORIG * 4);
  unsigned short* probs = (unsigned short*)alloc((size_t)Mc * ORIG * 2);

  int* cntW = hdr + 0;
  int* cntV = hdr + 1;
  float* acc = (float*)(hdr + 2);

  hipMemsetAsync(d_ws, 0, zero_bytes, stream);
  hipMemsetAsync(EW, 0, (size_t)MW_PAD * DIM * 4, stream);   // split-K atomic targets
  hipMemsetAsync(EV, 0, (size_t)MV_PAD * DIM * 4, stream);

  mark_ids<<<192, 256, 0, stream>>>(in_ids, pos_ids, neg_ids, flagW, flagV);
  compact<<<(NEWN + 255) / 256, 256, 0, stream>>>(flagW, listW, invW, cntW);
  compact<<<(NEWN + 255) / 256, 256, 0, stream>>>(flagV, listV, invV, cntV);

  tcvt<<<dim3(ORIG / 64, DIM / 64), 256, 0, stream>>>(AW2, AW2T, DIM, ORIG);  // ->[32000,1024]
  tcvt<<<dim3(ORIG / 64, DIM / 64), 256, 0, stream>>>(AV2, AV2T, DIM, ORIG);
  tcvt<<<dim3(DIM / 64, ORIG / 64), 256, 0, stream>>>(Wo, WoT, ORIG, DIM);    // ->[1024,32000]
  tcvt<<<dim3(DIM / 64, ORIG / 64), 256, 0, stream>>>(Vo, VoT, ORIG, DIM);

  gather_rows<<<MW_PAD, 256, 0, stream>>>(AW1, listW, cntW, A1Wg);
  gather_rows<<<MV_PAD, 256, 0, stream>>>(AV1, listV, cntV, A1Vg);

  // W side: GEMM1 (logits, K=1024) -> softmax -> GEMM2 (K=32000, split-K=4)
  int nW = MW_PAD / Mc;
  for (int c = 0; c < nW; ++c) {
    int b = c * Mc;
    gemm_bt<0><<<dim3(ORIG / 128, Mc / 128, 1), 256, 0, stream>>>(
        A1Wg + (size_t)b * DIM, DIM, AW2T, DIM, logits, ORIG, cntW, b, DIM);
    softmax_rows<<<Mc, 256, 0, stream>>>(logits, probs, sumsW + b, cntW, b);
    gemm_bt<1><<<dim3(DIM / 128, Mc / 128, 4), 256, 0, stream>>>(
        probs, ORIG, WoT, ORIG, EW + (size_t)b * DIM, DIM, cntW, b, ORIG / 4);
  }
  int nV = MV_PAD / Mc;
  for (int c = 0; c < nV; ++c) {
    int b = c * Mc;
    gemm_bt<0><<<dim3(ORIG / 128, Mc / 128, 1), 256, 0, stream>>>(
        A1Vg + (size_t)b * DIM, DIM, AV2T, DIM, logits, ORIG, cntV, b, DIM);
    softmax_rows<<<Mc, 256, 0, stream>>>(logits, probs, sumsV + b, cntV, b);
    gemm_bt<1><<<dim3(DIM / 128, Mc / 128, 4), 256, 0, stream>>>(
        probs, ORIG, VoT, ORIG, EV + (size_t)b * DIM, DIM, cntV, b, ORIG / 4);
  }
  scale_rows<<<MW_PAD, 256, 0, stream>>>(EW, sumsW, cntW);
  scale_rows<<<MV_PAD, 256, 0, stream>>>(EV, sumsV, cntV);

  score_loss<<<BB, 256, 0, stream>>>(Wo, Vo, EW, EV, invW, invV,
                                     in_ids, pos_ids, neg_ids, acc);
  finalize<<<1, 64, 0, stream>>>(acc, out);
}